// Round 1
// baseline (19778.848 us; speedup 1.0000x reference)
//
#include <hip/hip_runtime.h>
#include <hip/hip_bf16.h>
#include <math.h>

// ---------------- problem constants ----------------
#define NN     4096      // nodes
#define INLEN  564       // input length per node
#define P1LEN  278       // global conv1 output positions
#define P1PAD  280
#define NT     24        // enc+dec steps
#define NC1    32
#define NC2    64
#define KS     10
#define L2     66
#define EPS    1e-5f

// ---------------- workspace layout (float offsets) ----------------
static const long O_COLS  = 0;          // 8960
static const long O_COLSQ = 8960;       // 8960
static const long O_STATS = 17920;      // 24*128
static const long O_H     = 20992;      // 4096*64
static const long ZERO_FLOATS = 283136; // everything above is zeroed each call
static const long O_A1    = 283136;     // 24*32
static const long O_D1    = 283904;     // 24*32
static const long O_W2E   = 284672;     // 24*64*320
static const long O_CB2   = 776192;     // 24*64
static const long O_EMBS  = 777728;     // 24*4096*64
static const long O_X     = 7069184;    // 4096*128
static const long O_T1    = 7593472;
static const long O_T2    = 8117760;
static const long O_RH    = 8642048;    // 4096*64
static const long O_U     = 8904192;
static const long O_P1    = 9166336;
static const long O_P2    = 9428480;
static const long O_PP    = 9690624;    // mm partials, 4096*832 max
static const long O_UN    = 13098496;   // union region
// phase1 (embedding): g1 bf16 at O_UN (36,700,160 elems = 18,350,080 float slots), y2 after
static const long O_Y2    = O_UN + 18350080;   // 4096*64*66 floats
// phase2 (decoder): overlays union region
static const long O_EB    = O_UN;                 // 4096*832
static const long O_AE1   = O_UN + 3407872;
static const long O_AE2   = O_UN + 6815744;
static const long O_RHB   = O_UN + 10223616;      // 4096*768
static const long O_P1B   = O_UN + 13369344;
static const long O_P2B   = O_UN + 16515072;
static const long O_UD    = O_UN + 19660800;      // 49152*64
static const long O_HD    = O_UN + 22806528;      // 49152*64

struct Src { const float* p; int ld; int off; int tmul; };

// ---------------- conv1 (global, shared across windows), relu, store bf16 ----------------
__global__ __launch_bounds__(256) void k_conv1(const float* __restrict__ inp,
    const float* __restrict__ w1, const float* __restrict__ b1,
    __hip_bfloat16* __restrict__ g1) {
  long gid = (long)blockIdx.x*256 + threadIdx.x;   // over 4096*32*280
  int p = (int)(gid % P1PAD);
  long rem = gid / P1PAD;
  int c = (int)(rem % NC1);
  int n = (int)(rem / NC1);
  if (n >= NN || p >= P1LEN) return;
  const float* ip = inp + (long)n*INLEN + 2*p;
  const float* wp = w1 + c*KS;
  float acc = b1[c];
  #pragma unroll
  for (int k=0;k<KS;k++) acc = fmaf(wp[k], ip[k], acc);
  acc = fmaxf(acc, 0.f);
  g1[((long)n*NC1 + c)*P1PAD + p] = __float2bfloat16(acc);
}

// ---------------- per-(c,p) column sums over n for BN1 stats ----------------
__global__ __launch_bounds__(256) void k_colsum(const __hip_bfloat16* __restrict__ g1,
    float* __restrict__ colS, float* __restrict__ colSQ) {
  int col = blockIdx.x*256 + threadIdx.x;  // c*280+p
  if (col >= NC1*P1PAD) return;
  int n0 = blockIdx.y*512;
  float s = 0.f, sq = 0.f;
  for (int n=n0; n<n0+512; n++) {
    float v = __bfloat162float(g1[(long)n*(NC1*P1PAD) + col]);
    s += v; sq += v*v;
  }
  atomicAdd(&colS[col], s);
  atomicAdd(&colSQ[col], sq);
}

// ---------------- BN1 affine per (t,c) ----------------
__global__ __launch_bounds__(64) void k_bn1aff(const float* __restrict__ colS,
    const float* __restrict__ colSQ, const float* __restrict__ g, const float* __restrict__ b,
    float* __restrict__ a1, float* __restrict__ d1) {
  int i = blockIdx.x*64 + threadIdx.x;
  if (i >= NT*NC1) return;
  int t = i / NC1, c = i % NC1;
  float s=0.f, sq=0.f;
  for (int p=6*t; p<6*t+140; p++) { s += colS[c*P1PAD+p]; sq += colSQ[c*P1PAD+p]; }
  float cnt = 4096.f*140.f;
  float m = s/cnt;
  float v = sq/cnt - m*m;
  float a = g[c]*rsqrtf(v+EPS);
  a1[i] = a;
  d1[i] = b[c] - m*a;
}

// ---------------- fold BN1 affine into conv2 weights ----------------
__global__ __launch_bounds__(256) void k_w2eff(const float* __restrict__ w2,
    const float* __restrict__ b2, const float* __restrict__ a1, const float* __restrict__ d1,
    float* __restrict__ w2e, float* __restrict__ cb2) {
  int i = blockIdx.x*256 + threadIdx.x;   // t*64+c2
  if (i >= NT*NC2) return;
  int t = i/NC2, c2 = i%NC2;
  float cb = b2[c2];
  for (int c1=0;c1<NC1;c1++) {
    float a = a1[t*NC1+c1], d = d1[t*NC1+c1];
    float wsum = 0.f;
    for (int k=0;k<KS;k++) {
      float w = w2[(c2*NC1+c1)*KS+k];
      wsum += w;
      w2e[((long)t*NC2+c2)*320 + c1*KS+k] = w*a;
    }
    cb += wsum*d;
  }
  cb2[i] = cb;
}

// ---------------- conv2 + relu + BN2-stat accumulation, one t ----------------
// block = 2 nodes, 384 threads = (64 c2) x (6 grp), grp -> (node, 22-l2 span)
__global__ __launch_bounds__(384) void k_conv2(const __hip_bfloat16* __restrict__ g1,
    const float* __restrict__ w2e, const float* __restrict__ cb2,
    float* __restrict__ y2, float* __restrict__ stats, int t) {
  __shared__ float patch[2][NC1][144];   // 36,864 B
  __shared__ float wl[NC2][81];          // 20,736 B (chunked: 8 c1 at a time)
  __shared__ float red[6][NC2];          // 1,536 B
  int tid = threadIdx.x;
  int n0 = blockIdx.x*2;
  for (int i=tid; i<2*NC1*140; i+=384) {
    int nn = i/(NC1*140), r = i%(NC1*140), c1 = r/140, q = r%140;
    patch[nn][c1][q] = __bfloat162float(g1[((long)(n0+nn)*NC1 + c1)*P1PAD + 6*t + q]);
  }
  int c2 = tid & 63, grp = tid >> 6;
  int nnn = grp/3, l2b = (grp%3)*22;
  float acc[22];
  #pragma unroll
  for (int j=0;j<22;j++) acc[j] = 0.f;
  for (int c1g=0; c1g<4; c1g++) {
    __syncthreads();
    for (int i=tid; i<NC2*80; i+=384) {
      int cc = i/80, kk = i%80;
      wl[cc][kk] = w2e[((long)t*NC2+cc)*320 + c1g*80 + kk];
    }
    __syncthreads();
    for (int c1l=0; c1l<8; c1l++) {
      int c1 = c1g*8 + c1l;
      float pv[52];
      const float* pp = &patch[nnn][c1][2*l2b];
      #pragma unroll
      for (int q=0;q<13;q++) {
        float4 v = *(const float4*)(pp + 4*q);
        pv[4*q]=v.x; pv[4*q+1]=v.y; pv[4*q+2]=v.z; pv[4*q+3]=v.w;
      }
      const float* wp = &wl[c2][c1l*10];
      #pragma unroll
      for (int k=0;k<KS;k++) {
        float w = wp[k];
        #pragma unroll
        for (int j=0;j<22;j++) acc[j] = fmaf(w, pv[k+2*j], acc[j]);
      }
    }
  }
  float cb = cb2[t*NC2+c2];
  float s=0.f, sq=0.f;
  #pragma unroll
  for (int j=0;j<22;j++) {
    float v = fmaxf(acc[j]+cb, 0.f);
    s += v; sq += v*v;
    y2[((long)(n0+nnn)*NC2 + c2)*L2 + l2b + j] = v;
  }
  red[grp][c2] = s;  __syncthreads();
  if (grp==0) { float tot=0.f; for (int g2=0; g2<6; g2++) tot += red[g2][c2]; atomicAdd(&stats[t*128+c2], tot); }
  __syncthreads();
  red[grp][c2] = sq; __syncthreads();
  if (grp==0) { float tot=0.f; for (int g2=0; g2<6; g2++) tot += red[g2][c2]; atomicAdd(&stats[t*128+64+c2], tot); }
}

// ---------------- BN2 + fcconv + relu + fc -> embedding, one t ----------------
__global__ __launch_bounds__(256) void k_pass2(const float* __restrict__ y2,
    const float* __restrict__ stats, const float* __restrict__ bn2g, const float* __restrict__ bn2b,
    const float* __restrict__ fcvw, const float* __restrict__ fcvb,
    const float* __restrict__ fcW, const float* __restrict__ fcB,
    float* __restrict__ embs, int t) {
  __shared__ float fwa[64];
  __shared__ float cfcs[64];
  __shared__ float zbuf[8][66];
  __shared__ float fw[66*64];
  int tid = threadIdx.x;
  if (tid < 64) {
    float cnt = 4096.f*66.f;
    float m = stats[t*128+tid]/cnt;
    float v = stats[t*128+64+tid]/cnt - m*m;
    float a = bn2g[tid]*rsqrtf(v+EPS);
    float d = bn2b[tid] - m*a;
    fwa[tid]  = fcvw[tid]*a;
    cfcs[tid] = fcvw[tid]*d;
  }
  for (int i=tid; i<66*64; i+=256) fw[i] = fcW[i];
  __syncthreads();
  float cfc = fcvb[0];
  #pragma unroll 8
  for (int c=0;c<64;c++) cfc += cfcs[c];
  int n0 = blockIdx.x*8;
  for (int idx=tid; idx<8*66; idx+=256) {
    int nn = idx/66, l = idx%66;
    const float* yp = y2 + (long)(n0+nn)*NC2*L2 + l;
    float z = cfc;
    #pragma unroll 8
    for (int c=0;c<64;c++) z = fmaf(fwa[c], yp[c*L2], z);
    zbuf[nn][l] = fmaxf(z, 0.f);
  }
  __syncthreads();
  for (int idx=tid; idx<8*64; idx+=256) {
    int nn = idx/64, e = idx%64;
    float acc = fcB[e];
    for (int l=0;l<66;l++) acc = fmaf(zbuf[nn][l], fw[l*64+e], acc);
    embs[((long)t*NN + n0+nn)*64 + e] = acc;
  }
}

// ---------------- X = [emb_t, h] ----------------
__global__ __launch_bounds__(256) void k_buildX(const float* __restrict__ et,
    const float* __restrict__ h, float* __restrict__ X) {
  int gid = blockIdx.x*256 + threadIdx.x;   // 4096*128
  int n = gid >> 7, c = gid & 127;
  X[gid] = (c < 64) ? et[(long)n*64 + c] : h[(long)n*64 + (c-64)];
}

// ---------------- Ebig2 = [emb_12..emb_23 | h], 4096 x 832 ----------------
__global__ __launch_bounds__(256) void k_gatherE(const float* __restrict__ embs,
    const float* __restrict__ h, float* __restrict__ E) {
  int gid = blockIdx.x*256 + threadIdx.x;   // 4096*832
  int n = gid / 832, c = gid % 832;
  E[gid] = (c < 768) ? embs[((long)(12 + c/64)*NN + n)*64 + (c & 63)]
                     : h[(long)n*64 + (c & 63)];
}

// ---------------- C = adj @ B   (M=4096, K=4096, N multiple of 64) ----------------
// 64-thread block, 64x64 tile, 8x8 per-thread register blocking, split-K via blockIdx.z
__global__ __launch_bounds__(64) void k_mm(const float* __restrict__ A,
    const float* __restrict__ B, int ldb, float* __restrict__ P, int N, int kch) {
  __shared__ float As[32][64];
  __shared__ float Bs[32][64];
  int tid = threadIdx.x;
  long Mb = (long)blockIdx.x*64;
  int Nb = blockIdx.y*64;
  int k0 = blockIdx.z*kch;
  int tm = tid >> 3, tn = tid & 7;
  float acc[8][8];
  #pragma unroll
  for (int i=0;i<8;i++)
    #pragma unroll
    for (int j=0;j<8;j++) acc[i][j]=0.f;
  for (int kc=k0; kc<k0+kch; kc+=32) {
    __syncthreads();
    const float* ap = A + (Mb+tid)*4096 + kc;
    #pragma unroll
    for (int q=0;q<8;q++) {
      float4 v = *(const float4*)(ap + 4*q);
      As[4*q+0][tid]=v.x; As[4*q+1][tid]=v.y; As[4*q+2][tid]=v.z; As[4*q+3][tid]=v.w;
    }
    #pragma unroll
    for (int kk=0;kk<32;kk++) Bs[kk][tid] = B[(long)(kc+kk)*ldb + Nb + tid];
    __syncthreads();
    #pragma unroll
    for (int kk=0;kk<32;kk++) {
      const float4 a0 = *(const float4*)&As[kk][tm*8];
      const float4 a1 = *(const float4*)&As[kk][tm*8+4];
      const float4 b0 = *(const float4*)&Bs[kk][tn*8];
      const float4 b1 = *(const float4*)&Bs[kk][tn*8+4];
      float av[8] = {a0.x,a0.y,a0.z,a0.w,a1.x,a1.y,a1.z,a1.w};
      float bv[8] = {b0.x,b0.y,b0.z,b0.w,b1.x,b1.y,b1.z,b1.w};
      #pragma unroll
      for (int i=0;i<8;i++)
        #pragma unroll
        for (int j=0;j<8;j++) acc[i][j] = fmaf(av[i], bv[j], acc[i][j]);
    }
  }
  float* pp = P + (long)blockIdx.z*4096*N;
  #pragma unroll
  for (int i=0;i<8;i++) {
    long ro = (Mb + tm*8 + i)*N + Nb + tn*8;
    float4 v0 = make_float4(acc[i][0],acc[i][1],acc[i][2],acc[i][3]);
    float4 v1 = make_float4(acc[i][4],acc[i][5],acc[i][6],acc[i][7]);
    *(float4*)&pp[ro]   = v0;
    *(float4*)&pp[ro+4] = v1;
  }
}

// ---------------- reduce split-K partials; mode1: dst = 2*sum - Xref ----------------
__global__ __launch_bounds__(256) void k_red(const float* __restrict__ P,
    float* __restrict__ dst, const float* __restrict__ Xref, int total, int ksplit, int mode) {
  int gid = blockIdx.x*256 + threadIdx.x;
  if (gid >= total) return;
  float a = 0.f;
  for (int s=0;s<ksplit;s++) a += P[(long)s*total + gid];
  if (mode == 1) a = 2.f*a - Xref[gid];
  dst[gid] = a;
}

// ---------------- gather-GEMM: [6 col-block sources] @ W + bias, fused DCGRU epilogue ----
// mode 0 (gate): cols<64 -> o1 = sigmoid*h (rh), cols>=64 -> o2 = sigmoid (u)
// mode 1 (cand): o1 = u*h + (1-u)*tanh(g), o2 = u (input)
__global__ __launch_bounds__(256) void k_ggemm(
    Src s0, Src s1, Src s2, Src s3, Src s4, Src s5,
    const float* __restrict__ W, const float* __restrict__ bias, int N, int mode,
    float* __restrict__ o1, int ld1, int t1, float* __restrict__ o2,
    const float* __restrict__ h) {
  __shared__ float Ags[32][17];
  __shared__ float Bgs[32][64];
  int tid = threadIdx.x;
  int Mb = blockIdx.x*16, Nb = blockIdx.y*64;
  float acc[4] = {0.f,0.f,0.f,0.f};
  for (int c0=0; c0<384; c0+=32) {
    Src S;
    switch (c0 >> 6) {
      case 0: S = s0; break; case 1: S = s1; break; case 2: S = s2; break;
      case 3: S = s3; break; case 4: S = s4; break; default: S = s5; break;
    }
    int cc0 = c0 & 63;
    __syncthreads();
    #pragma unroll
    for (int h0=0; h0<2; h0++) {
      int idx = tid + h0*256;
      int mm_ = idx >> 5, kk = idx & 31;
      int row = Mb + mm_, tt = row >> 12, n = row & 4095;
      Ags[kk][mm_] = S.p[(long)n*S.ld + S.off + S.tmul*(tt*64) + cc0 + kk];
    }
    #pragma unroll
    for (int j=0;j<8;j++) {
      int kk = (tid >> 6) + j*4;
      Bgs[kk][tid & 63] = W[(long)(c0+kk)*N + Nb + (tid & 63)];
    }
    __syncthreads();
    #pragma unroll
    for (int kk=0;kk<32;kk++) {
      float a = Ags[kk][tid >> 4];
      const float4 b4 = *(const float4*)&Bgs[kk][(tid & 15)*4];
      acc[0] = fmaf(a, b4.x, acc[0]);
      acc[1] = fmaf(a, b4.y, acc[1]);
      acc[2] = fmaf(a, b4.z, acc[2]);
      acc[3] = fmaf(a, b4.w, acc[3]);
    }
  }
  int row = Mb + (tid >> 4), tt = row >> 12, n = row & 4095;
  #pragma unroll
  for (int j=0;j<4;j++) {
    int col = Nb + (tid & 15)*4 + j;
    float g = acc[j] + bias[col];
    if (mode == 0) {
      float sg = 1.f/(1.f + expf(-g));
      if (col < 64) o1[(long)n*ld1 + t1*tt*64 + col] = sg * h[(long)n*64 + col];
      else          o2[(long)row*64 + (col - 64)] = sg;
    } else {
      float uu = o2[(long)row*64 + col];
      o1[(long)row*64 + col] = uu*h[(long)n*64 + col] + (1.f - uu)*tanhf(g);
    }
  }
}

// ---------------- preds = h_dec @ pred_w + pred_b, transposed write ----------------
__global__ __launch_bounds__(256) void k_pred(const float* __restrict__ hd,
    const float* __restrict__ pw, const float* __restrict__ pb, float* __restrict__ out) {
  int gid = blockIdx.x*256 + threadIdx.x;
  int wid = gid >> 6;           // one row per wave
  int lane = threadIdx.x & 63;
  if (wid >= 12*NN) return;
  int t = wid >> 12, n = wid & 4095;
  float hv = hd[(long)wid*64 + lane];
  float res = 0.f;
  #pragma unroll
  for (int p=0;p<12;p++) {
    float v = hv * pw[lane*12 + p];
    #pragma unroll
    for (int off=32; off>0; off>>=1) v += __shfl_xor(v, off, 64);
    if (lane == p) res = v + pb[p];
  }
  if (lane < 12) out[(long)n*144 + t*12 + lane] = res;
}

// ============================================================================
extern "C" void kernel_launch(void* const* d_in, const int* in_sizes, int n_in,
                              void* d_out, int out_size, void* d_ws, size_t ws_size,
                              hipStream_t stream) {
  const float* inp  = (const float*)d_in[0];
  const float* c1w  = (const float*)d_in[2];
  const float* c1b  = (const float*)d_in[3];
  const float* c2w  = (const float*)d_in[4];
  const float* c2b  = (const float*)d_in[5];
  const float* bn1g = (const float*)d_in[6];
  const float* bn1b = (const float*)d_in[7];
  const float* bn2g = (const float*)d_in[8];
  const float* bn2b = (const float*)d_in[9];
  const float* fcvw = (const float*)d_in[10];
  const float* fcvb = (const float*)d_in[11];
  const float* fcW  = (const float*)d_in[12];
  const float* fcB  = (const float*)d_in[13];
  const float* eWg  = (const float*)d_in[14];
  const float* ebg  = (const float*)d_in[15];
  const float* eWc  = (const float*)d_in[16];
  const float* ebc  = (const float*)d_in[17];
  const float* dWg  = (const float*)d_in[18];
  const float* dbg  = (const float*)d_in[19];
  const float* dWc  = (const float*)d_in[20];
  const float* dbc  = (const float*)d_in[21];
  const float* pw   = (const float*)d_in[22];
  const float* pb   = (const float*)d_in[23];
  const float* adj  = (const float*)d_in[n_in-1];
  for (int i=0;i<n_in;i++) if (in_sizes[i] == NN*NN) adj = (const float*)d_in[i];

  float* ws = (float*)d_ws;
  float* colS  = ws + O_COLS;
  float* colSQ = ws + O_COLSQ;
  float* stats = ws + O_STATS;
  float* h     = ws + O_H;
  float* a1    = ws + O_A1;
  float* d1    = ws + O_D1;
  float* w2e   = ws + O_W2E;
  float* cb2   = ws + O_CB2;
  float* embs  = ws + O_EMBS;
  float* X     = ws + O_X;
  float* T1    = ws + O_T1;
  float* T2    = ws + O_T2;
  float* rh    = ws + O_RH;
  float* u     = ws + O_U;
  float* P1s   = ws + O_P1;
  float* P2s   = ws + O_P2;
  float* Pp    = ws + O_PP;
  __hip_bfloat16* g1 = (__hip_bfloat16*)(ws + O_UN);
  float* y2    = ws + O_Y2;
  float* Eb    = ws + O_EB;
  float* AE1   = ws + O_AE1;
  float* AE2   = ws + O_AE2;
  float* RHb   = ws + O_RHB;
  float* P1B   = ws + O_P1B;
  float* P2B   = ws + O_P2B;
  float* ud    = ws + O_UD;
  float* hd    = ws + O_HD;

  auto S = [](const float* p, int ld, int off, int tmul){ Src s; s.p=p; s.ld=ld; s.off=off; s.tmul=tmul; return s; };

  hipMemsetAsync(ws, 0, ZERO_FLOATS*sizeof(float), stream);

  // ---- embedding ----
  k_conv1 <<<143360, 256, 0, stream>>>(inp, c1w, c1b, g1);
  k_colsum<<<dim3(35,8), 256, 0, stream>>>(g1, colS, colSQ);
  k_bn1aff<<<12, 64, 0, stream>>>(colS, colSQ, bn1g, bn1b, a1, d1);
  k_w2eff <<<6, 256, 0, stream>>>(c2w, c2b, a1, d1, w2e, cb2);
  for (int t=0; t<NT; t++) {
    k_conv2<<<2048, 384, 0, stream>>>(g1, w2e, cb2, y2, stats, t);
    k_pass2<<<512, 256, 0, stream>>>(y2, stats, bn2g, bn2b, fcvw, fcvb, fcW, fcB, embs, t);
  }

  // ---- encoder (12 sequential DCGRU cells) ----
  for (int t=0; t<12; t++) {
    const float* et = embs + (long)t*NN*64;
    k_buildX<<<2048, 256, 0, stream>>>(et, h, X);
    k_mm <<<dim3(64,2,2), 64, 0, stream>>>(adj, X, 128, Pp, 128, 2048);
    k_red<<<2048, 256, 0, stream>>>(Pp, T1, (const float*)nullptr, 524288, 2, 0);
    k_mm <<<dim3(64,2,2), 64, 0, stream>>>(adj, T1, 128, Pp, 128, 2048);
    k_red<<<2048, 256, 0, stream>>>(Pp, T2, X, 524288, 2, 1);
    k_ggemm<<<dim3(256,2), 256, 0, stream>>>(
        S(X,128,0,0), S(X,128,64,0), S(T1,128,0,0), S(T1,128,64,0), S(T2,128,0,0), S(T2,128,64,0),
        eWg, ebg, 128, 0, rh, 64, 0, u, h);
    k_mm <<<dim3(64,1,4), 64, 0, stream>>>(adj, rh, 64, Pp, 64, 1024);
    k_red<<<1024, 256, 0, stream>>>(Pp, P1s, (const float*)nullptr, 262144, 4, 0);
    k_mm <<<dim3(64,1,4), 64, 0, stream>>>(adj, P1s, 64, Pp, 64, 1024);
    k_red<<<1024, 256, 0, stream>>>(Pp, P2s, rh, 262144, 4, 1);
    k_ggemm<<<dim3(256,1), 256, 0, stream>>>(
        S(et,64,0,0), S(rh,64,0,0), S(T1,128,0,0), S(P1s,64,0,0), S(T2,128,0,0), S(P2s,64,0,0),
        eWc, ebc, 64, 1, h, 0, 0, u, h);   // in-place h update
  }

  // ---- decoder (batched over 12 steps) ----
  k_gatherE<<<13312, 256, 0, stream>>>(embs, h, Eb);
  k_mm <<<dim3(64,13,1), 64, 0, stream>>>(adj, Eb, 832, AE1, 832, 4096);
  k_mm <<<dim3(64,13,1), 64, 0, stream>>>(adj, AE1, 832, Pp, 832, 4096);
  k_red<<<13312, 256, 0, stream>>>(Pp, AE2, Eb, 3407872, 1, 1);
  k_ggemm<<<dim3(3072,2), 256, 0, stream>>>(
      S(Eb,832,0,1), S(Eb,832,768,0), S(AE1,832,0,1), S(AE1,832,768,0), S(AE2,832,0,1), S(AE2,832,768,0),
      dWg, dbg, 128, 0, RHb, 768, 1, ud, h);
  k_mm <<<dim3(64,12,1), 64, 0, stream>>>(adj, RHb, 768, P1B, 768, 4096);
  k_mm <<<dim3(64,12,1), 64, 0, stream>>>(adj, P1B, 768, Pp, 768, 4096);
  k_red<<<12288, 256, 0, stream>>>(Pp, P2B, RHb, 3145728, 1, 1);
  k_ggemm<<<dim3(3072,1), 256, 0, stream>>>(
      S(Eb,832,0,1), S(RHb,768,0,1), S(AE1,832,0,1), S(P1B,768,0,1), S(AE2,832,0,1), S(P2B,768,0,1),
      dWc, dbc, 64, 1, hd, 0, 0, ud, h);

  k_pred<<<12288, 256, 0, stream>>>(hd, pw, pb, (float*)d_out);
}

// Round 3
// 6206.951 us; speedup vs baseline: 3.1866x; 3.1866x over previous
//
#include <hip/hip_runtime.h>
#include <hip/hip_bf16.h>
#include <math.h>

// ---------------- problem constants ----------------
#define NN     4096
#define INLEN  564
#define NT     24
#define NC1    32
#define NC2    64
#define KS     10
#define L2     66
#define EPS    1e-5f

typedef short s8v __attribute__((ext_vector_type(8)));
typedef short s4v __attribute__((ext_vector_type(4)));
typedef float f4v __attribute__((ext_vector_type(4)));

// ---------------- workspace layout (float offsets) ----------------
static const long O_COLS   = 0;          // 8960
static const long O_COLSQ  = 8960;       // 8960
static const long O_STATS  = 17920;      // 24*128
static const long O_H      = 20992;      // 4096*64
static const long ZERO_FLOATS = 283136;
static const long O_A1     = 283136;     // 768
static const long O_D1     = 283904;     // 768
static const long O_CB2    = 284672;     // 1536
static const long O_W2B    = 286208;     // bf16 24*10*64*32 -> 122880 float slots
// ---- embedding phase ----
static const long O_G1P    = 532480;     // bf16 4096*280*32 -> 18,350,080 slots
static const long O_Y2     = 18882560;   // bf16 4096*64*68 (PER-T, reused) -> 8,912,896 slots
static const long O_EMBS   = 27795456;   // fp32 24*4096*64 = 6,291,456 -> end 34,086,912
// ---- encoder/decoder overlay (g1p/y2 dead) ----
static const long O_ADJB   = 532480;     // bf16 4096*4096 -> 8,388,608 slots
static const long O_PP     = 8921088;    // fp32 4,194,304 (enc partials; decoder hd)
static const long O_X      = 13115392;   // 524288   (decoder: P2B)
static const long O_XT     = 13639680;   // 262144 (bf16 128x4096)
static const long O_T1     = 13901824;   // 524288
static const long O_T1T    = 14426112;   // 262144
static const long O_T2     = 14688256;   // 524288
static const long O_RH     = 15212544;   // 262144
static const long O_RHT    = 15474688;   // 131072 (bf16 64x4096)
static const long O_P1S    = 15605760;   // 262144
static const long O_P1ST   = 15867904;   // 131072
static const long O_P2S    = 15998976;   // 262144
static const long O_UE     = 16261120;   // 131072 (bf16 4096*64)
// ---- decoder ----
static const long O_EB     = 16392192;   // fp32 4096*896 = 3,670,016
static const long O_EBT    = 20062208;   // bf16 896*4096 -> 1,835,008 (reused: RHbt, then P1Bt)
static const long O_AE1    = 21897216;   // 3,670,016
static const long O_AE1T   = 25567232;   // 1,835,008 (reused: ud bf16 49152*64 -> 1,572,864)
static const long O_AE2    = 27795456;   // 3,670,016 (overlays embs, dead by then)
static const long O_RHB    = 31465472;   // 3,145,728
static const long O_P1B    = 34611200;   // 3,145,728 -> peak end 37,756,928 floats = 151.0 MB
static const long O_P2B    = O_X;        // 3,145,728 (enc bufs dead)
static const long O_HD     = O_PP;       // 3,145,728

struct Src { const float* p; int ld; int off; int tmul; };

static __device__ __forceinline__ short bf16bits(float v) {
  __hip_bfloat16_raw r = __hip_bfloat16_raw(__float2bfloat16(v));
  return (short)r.x;
}

// ---------------- conv1 -> g1p[n][p][c1] bf16, relu ----------------
__global__ __launch_bounds__(256) void k_conv1p(const float* __restrict__ inp,
    const float* __restrict__ w1, const float* __restrict__ b1,
    __hip_bfloat16* __restrict__ g1p) {
  long gid = (long)blockIdx.x*256 + threadIdx.x;   // 4096*280*32
  int c = (int)(gid & 31);
  long r2 = gid >> 5;
  int p = (int)(r2 % 280);
  int n = (int)(r2 / 280);
  if (n >= NN) return;
  if (p >= 278) { g1p[gid] = __float2bfloat16(0.f); return; }
  const float* ip = inp + (long)n*INLEN + 2*p;
  const float* wp = w1 + c*KS;
  float acc = b1[c];
  #pragma unroll
  for (int k=0;k<KS;k++) acc = fmaf(wp[k], ip[k], acc);
  g1p[gid] = __float2bfloat16(fmaxf(acc, 0.f));
}

// ---------------- per-(p,c) column sums for BN1 ----------------
__global__ __launch_bounds__(256) void k_colsum(const __hip_bfloat16* __restrict__ g1p,
    float* __restrict__ colS, float* __restrict__ colSQ) {
  int col = blockIdx.x*256 + threadIdx.x;  // p*32+c
  if (col >= 280*32) return;
  int n0 = blockIdx.y*512;
  float s = 0.f, sq = 0.f;
  for (int n=n0; n<n0+512; n++) {
    float v = __bfloat162float(g1p[(long)n*8960 + col]);
    s += v; sq += v*v;
  }
  atomicAdd(&colS[col], s);
  atomicAdd(&colSQ[col], sq);
}

__global__ __launch_bounds__(64) void k_bn1aff(const float* __restrict__ colS,
    const float* __restrict__ colSQ, const float* __restrict__ g, const float* __restrict__ b,
    float* __restrict__ a1, float* __restrict__ d1) {
  int i = blockIdx.x*64 + threadIdx.x;
  if (i >= NT*NC1) return;
  int t = i / NC1, c = i % NC1;
  float s=0.f, sq=0.f;
  for (int p=6*t; p<6*t+140; p++) { s += colS[p*32+c]; sq += colSQ[p*32+c]; }
  float cnt = 4096.f*140.f;
  float m = s/cnt;
  float v = sq/cnt - m*m;
  float a = g[c]*rsqrtf(v+EPS);
  a1[i] = a;
  d1[i] = b[c] - m*a;
}

// ---------------- fold BN1 into conv2 weights: w2b[t][tap][c2][c1] bf16 ----------------
__global__ __launch_bounds__(256) void k_w2b(const float* __restrict__ w2,
    const float* __restrict__ b2, const float* __restrict__ a1, const float* __restrict__ d1,
    __hip_bfloat16* __restrict__ w2b, float* __restrict__ cb2) {
  int i = blockIdx.x*256 + threadIdx.x;   // t*64+c2
  if (i >= NT*NC2) return;
  int t = i>>6, c2 = i&63;
  float cb = b2[c2];
  for (int c1=0;c1<NC1;c1++) {
    float a = a1[t*32+c1], d = d1[t*32+c1];
    float wsum = 0.f;
    for (int k=0;k<KS;k++) {
      float wv = w2[(c2*32+c1)*KS+k];
      wsum += wv;
      w2b[(((long)t*10 + k)*64 + c2)*32 + c1] = __float2bfloat16(wv*a);
    }
    cb += wsum*d;
  }
  cb2[i] = cb;
}

// ---------------- conv2 as 10 accumulated MFMAs (K=c1=32), ONE t per launch ------
// block: 4 nodes (1 per wave); wave-tile 80(l2,pad)x64(c2); p = 2u+r, u=l2+j, tap=2j+r=s
__global__ __launch_bounds__(256) void k_conv2m(const __hip_bfloat16* __restrict__ g1p,
    const __hip_bfloat16* __restrict__ w2b, const float* __restrict__ cb2,
    __hip_bfloat16* __restrict__ y2, float* __restrict__ stats, int t) {
  __shared__ __attribute__((aligned(16))) short patch[4*140*40];   // padded rows: 40 shorts = 80B
  __shared__ float sS[64], sQ[64];
  int tid = threadIdx.x, w = tid>>6, lane = tid&63;
  int n0 = blockIdx.x*4;
  if (tid < 64) { sS[tid]=0.f; sQ[tid]=0.f; }
  const short* gp = (const short*)g1p;
  for (int f = tid; f < 2240; f += 256) {          // 4 nodes * 140 rows * 4 chunks
    int nn = f / 560, rr = f % 560;
    int row = rr >> 2, kq = rr & 3;
    s8v v = *(const s8v*)(gp + ((long)(n0+nn)*280 + 6*t + row)*32 + kq*8);
    *(s8v*)&patch[(nn*140 + row)*40 + kq*8] = v;
  }
  __syncthreads();
  int q = lane>>4, m = lane&15;
  f4v acc[5][4];
  #pragma unroll
  for (int a=0;a<5;a++)
    #pragma unroll
    for (int b=0;b<4;b++) acc[a][b] = (f4v){0.f,0.f,0.f,0.f};
  const short* wb = (const short*)w2b + (long)t*10*64*32;
  for (int s=0; s<10; s++) {
    int j = s>>1, r = s&1;
    s8v bfr[4];
    #pragma unroll
    for (int ng=0; ng<4; ng++)
      bfr[ng] = *(const s8v*)(wb + (long)(s*64 + ng*16 + m)*32 + q*8);
    #pragma unroll
    for (int mg=0; mg<5; mg++) {
      int l2 = mg*16 + m;
      int u = l2 + j; u = (u>69)?69:u;
      s8v afr = *(const s8v*)&patch[(w*140 + 2*u + r)*40 + q*8];
      #pragma unroll
      for (int ng=0; ng<4; ng++)
        acc[mg][ng] = __builtin_amdgcn_mfma_f32_16x16x32_bf16(afr, bfr[ng], acc[mg][ng], 0,0,0);
    }
  }
  int node = n0 + w;
  float s1a[4]={0,0,0,0}, s2a[4]={0,0,0,0};
  #pragma unroll
  for (int mg=0; mg<5; mg++) {
    int l2b = mg*16 + q*4;
    #pragma unroll
    for (int ng=0; ng<4; ng++) {
      int c2 = ng*16 + m;
      float cbv = cb2[t*64 + c2];
      float vv[4];
      #pragma unroll
      for (int rr=0; rr<4; rr++) {
        float v = fmaxf(acc[mg][ng][rr] + cbv, 0.f);
        vv[rr] = v;
        if (l2b + rr < 66) { s1a[ng] += v; s2a[ng] += v*v; }
      }
      long base = ((long)node*64 + c2)*68 + l2b;
      if (mg < 4) {
        s4v o;
        #pragma unroll
        for (int rr=0; rr<4; rr++) o[rr] = bf16bits(vv[rr]);
        *(s4v*)((short*)y2 + base) = o;
      } else {
        for (int rr=0; rr<4; rr++) if (l2b+rr < 66) y2[base+rr] = __float2bfloat16(vv[rr]);
      }
    }
  }
  #pragma unroll
  for (int ng=0; ng<4; ng++) {
    atomicAdd(&sS[ng*16+m], s1a[ng]);
    atomicAdd(&sQ[ng*16+m], s2a[ng]);
  }
  __syncthreads();
  if (tid < 64) {
    atomicAdd(&stats[t*128+tid], sS[tid]);
    atomicAdd(&stats[t*128+64+tid], sQ[tid]);
  }
}

// ---------------- BN2 + fcconv + relu + fc -> embedding, one t ----------------
__global__ __launch_bounds__(256) void k_pass2(const __hip_bfloat16* __restrict__ y2,
    const float* __restrict__ stats, const float* __restrict__ bn2g, const float* __restrict__ bn2b,
    const float* __restrict__ fcvw, const float* __restrict__ fcvb,
    const float* __restrict__ fcW, const float* __restrict__ fcB,
    float* __restrict__ embs, int t) {
  __shared__ float fwa[64];
  __shared__ float cfcs[64];
  __shared__ float zbuf[8][66];
  __shared__ float fw[66*64];
  int tid = threadIdx.x;
  if (tid < 64) {
    float cnt = 4096.f*66.f;
    float m = stats[t*128+tid]/cnt;
    float v = stats[t*128+64+tid]/cnt - m*m;
    float a = bn2g[tid]*rsqrtf(v+EPS);
    float d = bn2b[tid] - m*a;
    fwa[tid]  = fcvw[tid]*a;
    cfcs[tid] = fcvw[tid]*d;
  }
  for (int i=tid; i<66*64; i+=256) fw[i] = fcW[i];
  __syncthreads();
  float cfc = fcvb[0];
  #pragma unroll 8
  for (int c=0;c<64;c++) cfc += cfcs[c];
  int n0 = blockIdx.x*8;
  for (int idx=tid; idx<8*66; idx+=256) {
    int nn = idx/66, l = idx%66;
    const __hip_bfloat16* yp = y2 + (long)(n0+nn)*64*68 + l;
    float z = cfc;
    #pragma unroll 8
    for (int c=0;c<64;c++) z = fmaf(fwa[c], __bfloat162float(yp[c*68]), z);
    zbuf[nn][l] = fmaxf(z, 0.f);
  }
  __syncthreads();
  for (int idx=tid; idx<8*64; idx+=256) {
    int nn = idx/64, e = idx%64;
    float acc = fcB[e];
    for (int l=0;l<66;l++) acc = fmaf(zbuf[nn][l], fw[l*64+e], acc);
    embs[((long)t*NN + n0+nn)*64 + e] = acc;
  }
}

// ---------------- adj fp32 -> bf16 ----------------
__global__ __launch_bounds__(256) void k_cvtadj(const float* __restrict__ adj,
    __hip_bfloat16* __restrict__ adjb) {
  long gid = ((long)blockIdx.x*256 + threadIdx.x)*4;
  float4 v = *(const float4*)(adj + gid);
  adjb[gid+0] = __float2bfloat16(v.x);
  adjb[gid+1] = __float2bfloat16(v.y);
  adjb[gid+2] = __float2bfloat16(v.z);
  adjb[gid+3] = __float2bfloat16(v.w);
}

// ---------------- bf16 MFMA GEMM: P = adjb @ Bt^T ----------------
// Bt is bf16 [N][4096] (transposed). nwn=2: 128x128 tile; nwn=1: 256x64 tile. 4 waves.
__global__ __launch_bounds__(256) void k_mmb(const __hip_bfloat16* __restrict__ A,
    const __hip_bfloat16* __restrict__ Bt, float* __restrict__ P,
    int N, int kchunk, int nwn) {
  __shared__ __attribute__((aligned(16))) short As[4*256*8];
  __shared__ __attribute__((aligned(16))) short Bs[4*128*8];
  int tid = threadIdx.x;
  int w = tid >> 6, lane = tid & 63;
  int bmsh = (nwn==2) ? 7 : 8;
  int BM = 1 << bmsh;
  int BN = nwn << 6;
  int wm = (nwn==2) ? (w>>1) : w;
  int wn = (nwn==2) ? (w&1) : 0;
  long Mb = (long)blockIdx.x << bmsh;
  int Nb = blockIdx.y * BN;
  int k0 = blockIdx.z * kchunk;
  const short* Ag = (const short*)A;
  const short* Bg = (const short*)Bt;
  f4v acc[4][4];
  #pragma unroll
  for (int i=0;i<4;i++)
    #pragma unroll
    for (int j=0;j<4;j++) acc[i][j] = (f4v){0.f,0.f,0.f,0.f};
  int q = lane >> 4, m = lane & 15;
  for (int kc=k0; kc<k0+kchunk; kc+=32) {
    __syncthreads();
    for (int f = tid; f < (BM<<2); f += 256) {
      int row = f >> 2, qq = f & 3;
      s8v v = *(const s8v*)(Ag + (Mb + row)*4096 + kc + qq*8);
      *(s8v*)&As[((qq<<bmsh) + row)*8] = v;
    }
    for (int f = tid; f < (BN<<2); f += 256) {
      int col = f >> 2, qq = f & 3;
      s8v v = *(const s8v*)(Bg + (long)(Nb + col)*4096 + kc + qq*8);
      *(s8v*)&Bs[(qq*BN + col)*8] = v;
    }
    __syncthreads();
    s8v af[4], bf[4];
    #pragma unroll
    for (int i=0;i<4;i++) af[i] = *(const s8v*)&As[((q<<bmsh) + wm*64 + i*16 + m)*8];
    #pragma unroll
    for (int j=0;j<4;j++) bf[j] = *(const s8v*)&Bs[(q*BN + wn*64 + j*16 + m)*8];
    #pragma unroll
    for (int i=0;i<4;i++)
      #pragma unroll
      for (int j=0;j<4;j++)
        acc[i][j] = __builtin_amdgcn_mfma_f32_16x16x32_bf16(af[i], bf[j], acc[i][j], 0, 0, 0);
  }
  float* pp = P + (long)blockIdx.z * 4096L * N;
  #pragma unroll
  for (int i=0;i<4;i++) {
    long row0 = Mb + wm*64 + i*16 + q*4;
    #pragma unroll
    for (int j=0;j<4;j++) {
      int col = Nb + wn*64 + j*16 + m;
      #pragma unroll
      for (int r=0;r<4;r++)
        pp[(row0 + r)*N + col] = acc[i][j][r];
    }
  }
}

// ---------------- split-K reduce + optional (2x - ref) + optional transposed bf16 out ----
__global__ __launch_bounds__(256) void k_redT(const float* __restrict__ P,
    float* __restrict__ dst, const float* __restrict__ ref,
    __hip_bfloat16* __restrict__ dstT, int ldc, int ksplit, int mode,
    int writeF, int writeT) {
  __shared__ float tile[64][65];
  int tid = threadIdx.x;
  int n0 = blockIdx.x*64, c0 = blockIdx.y*64;
  long total = 4096L*ldc;
  for (int i=0; i<16; i++) {
    int flat = i*256 + tid;
    int cc = flat & 63, nn = flat >> 6;
    long idx = (long)(n0+nn)*ldc + c0+cc;
    float v = P[idx];
    for (int s=1; s<ksplit; s++) v += P[(long)s*total + idx];
    if (mode) v = 2.f*v - ref[idx];
    if (writeF) dst[idx] = v;
    tile[nn][cc] = v;
  }
  __syncthreads();
  if (writeT) {
    for (int i=0; i<16; i++) {
      int flat = i*256 + tid;
      int nn = flat & 63, cc = flat >> 6;
      dstT[(long)(c0+cc)*4096 + n0+nn] = __float2bfloat16(tile[nn][cc]);
    }
  }
}

// ---------------- X = [et|h] fp32 + Xt bf16 transposed ----------------
__global__ __launch_bounds__(256) void k_buildXT(const float* __restrict__ et,
    const float* __restrict__ h, float* __restrict__ X, __hip_bfloat16* __restrict__ Xt) {
  __shared__ float tile[64][65];
  int tid = threadIdx.x;
  int n0 = blockIdx.x*64, c0 = blockIdx.y*64;
  for (int i=0; i<16; i++) {
    int flat = i*256 + tid;
    int cc = flat & 63, nn = flat >> 6;
    int col = c0 + cc, n = n0 + nn;
    float v = (col < 64) ? et[(long)n*64 + col] : h[(long)n*64 + (col-64)];
    X[(long)n*128 + col] = v;
    tile[nn][cc] = v;
  }
  __syncthreads();
  for (int i=0; i<16; i++) {
    int flat = i*256 + tid;
    int nn = flat & 63, cc = flat >> 6;
    Xt[(long)(c0+cc)*4096 + n0+nn] = __float2bfloat16(tile[nn][cc]);
  }
}

// ---------------- Eb = [emb12..23 | h | 0pad] fp32 ld896 + Ebt bf16 ----------------
__global__ __launch_bounds__(256) void k_gatherE(const float* __restrict__ embs,
    const float* __restrict__ h, float* __restrict__ Eb, __hip_bfloat16* __restrict__ Ebt) {
  __shared__ float tile[64][65];
  int tid = threadIdx.x;
  int n0 = blockIdx.x*64, c0 = blockIdx.y*64;
  for (int i=0; i<16; i++) {
    int flat = i*256 + tid;
    int cc = flat & 63, nn = flat >> 6;
    int col = c0 + cc, n = n0 + nn;
    float v;
    if (col < 768)      v = embs[((long)(12 + (col>>6))*NN + n)*64 + (col & 63)];
    else if (col < 832) v = h[(long)n*64 + (col - 768)];
    else                v = 0.f;
    Eb[(long)n*896 + col] = v;
    tile[nn][cc] = v;
  }
  __syncthreads();
  for (int i=0; i<16; i++) {
    int flat = i*256 + tid;
    int nn = flat & 63, cc = flat >> 6;
    Ebt[(long)(c0+cc)*4096 + n0+nn] = __float2bfloat16(tile[nn][cc]);
  }
}

// ---------------- gather-GEMM + fused DCGRU epilogue (fp32 VALU) ----------------
__global__ __launch_bounds__(256) void k_ggemm(
    Src s0, Src s1, Src s2, Src s3, Src s4, Src s5,
    const float* __restrict__ W, const float* __restrict__ bias, int N, int mode,
    float* __restrict__ o1, int ld1, int t1, __hip_bfloat16* __restrict__ o1t,
    __hip_bfloat16* __restrict__ o2, const float* __restrict__ h) {
  __shared__ float Ags[32][17];
  __shared__ float Bgs[32][64];
  int tid = threadIdx.x;
  int Mb = blockIdx.x*16, Nb = blockIdx.y*64;
  float acc[4] = {0.f,0.f,0.f,0.f};
  for (int c0=0; c0<384; c0+=32) {
    Src S;
    switch (c0 >> 6) {
      case 0: S = s0; break; case 1: S = s1; break; case 2: S = s2; break;
      case 3: S = s3; break; case 4: S = s4; break; default: S = s5; break;
    }
    int cc0 = c0 & 63;
    __syncthreads();
    #pragma unroll
    for (int h0=0; h0<2; h0++) {
      int idx = tid + h0*256;
      int mm_ = idx >> 5, kk = idx & 31;
      int row = Mb + mm_, tt = row >> 12, n = row & 4095;
      Ags[kk][mm_] = S.p[(long)n*S.ld + S.off + S.tmul*(tt*64) + cc0 + kk];
    }
    #pragma unroll
    for (int j=0;j<8;j++) {
      int kk = (tid >> 6) + j*4;
      Bgs[kk][tid & 63] = W[(long)(c0+kk)*N + Nb + (tid & 63)];
    }
    __syncthreads();
    #pragma unroll
    for (int kk=0;kk<32;kk++) {
      float a = Ags[kk][tid >> 4];
      const float4 b4 = *(const float4*)&Bgs[kk][(tid & 15)*4];
      acc[0] = fmaf(a, b4.x, acc[0]);
      acc[1] = fmaf(a, b4.y, acc[1]);
      acc[2] = fmaf(a, b4.z, acc[2]);
      acc[3] = fmaf(a, b4.w, acc[3]);
    }
  }
  int row = Mb + (tid >> 4), tt = row >> 12, n = row & 4095;
  #pragma unroll
  for (int j=0;j<4;j++) {
    int col = Nb + (tid & 15)*4 + j;
    float g = acc[j] + bias[col];
    if (mode == 0) {
      float sg = 1.f/(1.f + expf(-g));
      if (col < 64) {
        float v = sg * h[(long)n*64 + col];
        o1[(long)n*ld1 + t1*tt*64 + col] = v;
        o1t[(long)(t1*tt*64 + col)*4096 + n] = __float2bfloat16(v);
      } else {
        o2[(long)row*64 + (col - 64)] = __float2bfloat16(sg);
      }
    } else {
      float uu = __bfloat162float(o2[(long)row*64 + col]);
      o1[(long)row*64 + col] = uu*h[(long)n*64 + col] + (1.f - uu)*tanhf(g);
    }
  }
}

// ---------------- preds ----------------
__global__ __launch_bounds__(256) void k_pred(const float* __restrict__ hd,
    const float* __restrict__ pw, const float* __restrict__ pb, float* __restrict__ out) {
  int gid = blockIdx.x*256 + threadIdx.x;
  int wid = gid >> 6;
  int lane = threadIdx.x & 63;
  if (wid >= 12*NN) return;
  int t = wid >> 12, n = wid & 4095;
  float hv = hd[(long)wid*64 + lane];
  float res = 0.f;
  #pragma unroll
  for (int p=0;p<12;p++) {
    float v = hv * pw[lane*12 + p];
    #pragma unroll
    for (int off=32; off>0; off>>=1) v += __shfl_xor(v, off, 64);
    if (lane == p) res = v + pb[p];
  }
  if (lane < 12) out[(long)n*144 + t*12 + lane] = res;
}

// ============================================================================
extern "C" void kernel_launch(void* const* d_in, const int* in_sizes, int n_in,
                              void* d_out, int out_size, void* d_ws, size_t ws_size,
                              hipStream_t stream) {
  const float* inp  = (const float*)d_in[0];
  const float* c1w  = (const float*)d_in[2];
  const float* c1b  = (const float*)d_in[3];
  const float* c2w  = (const float*)d_in[4];
  const float* c2b  = (const float*)d_in[5];
  const float* bn1g = (const float*)d_in[6];
  const float* bn1b = (const float*)d_in[7];
  const float* bn2g = (const float*)d_in[8];
  const float* bn2b = (const float*)d_in[9];
  const float* fcvw = (const float*)d_in[10];
  const float* fcvb = (const float*)d_in[11];
  const float* fcW  = (const float*)d_in[12];
  const float* fcB  = (const float*)d_in[13];
  const float* eWg  = (const float*)d_in[14];
  const float* ebg  = (const float*)d_in[15];
  const float* eWc  = (const float*)d_in[16];
  const float* ebc  = (const float*)d_in[17];
  const float* dWg  = (const float*)d_in[18];
  const float* dbg  = (const float*)d_in[19];
  const float* dWc  = (const float*)d_in[20];
  const float* dbc  = (const float*)d_in[21];
  const float* pw   = (const float*)d_in[22];
  const float* pb   = (const float*)d_in[23];
  const float* adj  = (const float*)d_in[n_in-1];
  for (int i=0;i<n_in;i++) if (in_sizes[i] == NN*NN) adj = (const float*)d_in[i];

  float* ws = (float*)d_ws;
  float* colS  = ws + O_COLS;
  float* colSQ = ws + O_COLSQ;
  float* stats = ws + O_STATS;
  float* h     = ws + O_H;
  float* a1    = ws + O_A1;
  float* d1    = ws + O_D1;
  float* cb2   = ws + O_CB2;
  __hip_bfloat16* w2b = (__hip_bfloat16*)(ws + O_W2B);
  __hip_bfloat16* g1p = (__hip_bfloat16*)(ws + O_G1P);
  __hip_bfloat16* y2  = (__hip_bfloat16*)(ws + O_Y2);
  float* embs  = ws + O_EMBS;
  __hip_bfloat16* adjb = (__hip_bfloat16*)(ws + O_ADJB);
  float* Pp    = ws + O_PP;
  float* X     = ws + O_X;
  __hip_bfloat16* Xt  = (__hip_bfloat16*)(ws + O_XT);
  float* T1    = ws + O_T1;
  __hip_bfloat16* T1t = (__hip_bfloat16*)(ws + O_T1T);
  float* T2    = ws + O_T2;
  float* rh    = ws + O_RH;
  __hip_bfloat16* rht = (__hip_bfloat16*)(ws + O_RHT);
  float* P1s   = ws + O_P1S;
  __hip_bfloat16* P1st = (__hip_bfloat16*)(ws + O_P1ST);
  float* P2s   = ws + O_P2S;
  __hip_bfloat16* ue  = (__hip_bfloat16*)(ws + O_UE);
  float* Eb    = ws + O_EB;
  __hip_bfloat16* Ebt = (__hip_bfloat16*)(ws + O_EBT);   // later RHbt, then P1Bt
  float* AE1   = ws + O_AE1;
  __hip_bfloat16* AE1t = (__hip_bfloat16*)(ws + O_AE1T); // later ud
  float* AE2   = ws + O_AE2;
  float* RHb   = ws + O_RHB;
  float* P1B   = ws + O_P1B;
  float* P2B   = ws + O_P2B;
  float* hd    = ws + O_HD;
  __hip_bfloat16* RHbt = Ebt;
  __hip_bfloat16* P1Bt = Ebt;
  __hip_bfloat16* ud   = AE1t;

  auto S = [](const float* p, int ld, int off, int tmul){ Src s; s.p=p; s.ld=ld; s.off=off; s.tmul=tmul; return s; };

  hipMemsetAsync(ws, 0, ZERO_FLOATS*sizeof(float), stream);

  // ---- embedding ----
  k_conv1p<<<143360, 256, 0, stream>>>(inp, c1w, c1b, g1p);
  k_colsum<<<dim3(35,8), 256, 0, stream>>>(g1p, colS, colSQ);
  k_bn1aff<<<12, 64, 0, stream>>>(colS, colSQ, bn1g, bn1b, a1, d1);
  k_w2b   <<<6, 256, 0, stream>>>(c2w, c2b, a1, d1, w2b, cb2);
  // y2 is PER-T (reused) -> conv2m and pass2 must alternate per t (round-2 bug fix)
  for (int t=0; t<NT; t++) {
    k_conv2m<<<1024, 256, 0, stream>>>(g1p, w2b, cb2, y2, stats, t);
    k_pass2 <<<512, 256, 0, stream>>>(y2, stats, bn2g, bn2b, fcvw, fcvb, fcW, fcB, embs, t);
  }

  // ---- adj -> bf16 (g1p dead now) ----
  k_cvtadj<<<16384, 256, 0, stream>>>(adj, adjb);

  // ---- encoder ----
  for (int t=0; t<12; t++) {
    const float* et = embs + (long)t*NN*64;
    k_buildXT<<<dim3(64,2), 256, 0, stream>>>(et, h, X, Xt);
    k_mmb <<<dim3(32,1,8), 256, 0, stream>>>(adjb, Xt, Pp, 128, 512, 2);
    k_redT<<<dim3(64,2), 256, 0, stream>>>(Pp, T1, (const float*)nullptr, T1t, 128, 8, 0, 1, 1);
    k_mmb <<<dim3(32,1,8), 256, 0, stream>>>(adjb, T1t, Pp, 128, 512, 2);
    k_redT<<<dim3(64,2), 256, 0, stream>>>(Pp, T2, X, (__hip_bfloat16*)nullptr, 128, 8, 1, 1, 0);
    k_ggemm<<<dim3(256,2), 256, 0, stream>>>(
        S(X,128,0,0), S(X,128,64,0), S(T1,128,0,0), S(T1,128,64,0), S(T2,128,0,0), S(T2,128,64,0),
        eWg, ebg, 128, 0, rh, 64, 0, rht, ue, h);
    k_mmb <<<dim3(16,1,8), 256, 0, stream>>>(adjb, rht, Pp, 64, 512, 1);
    k_redT<<<dim3(64,1), 256, 0, stream>>>(Pp, P1s, (const float*)nullptr, P1st, 64, 8, 0, 1, 1);
    k_mmb <<<dim3(16,1,8), 256, 0, stream>>>(adjb, P1st, Pp, 64, 512, 1);
    k_redT<<<dim3(64,1), 256, 0, stream>>>(Pp, P2s, rh, (__hip_bfloat16*)nullptr, 64, 8, 1, 1, 0);
    k_ggemm<<<dim3(256,1), 256, 0, stream>>>(
        S(et,64,0,0), S(rh,64,0,0), S(T1,128,0,0), S(P1s,64,0,0), S(T2,128,0,0), S(P2s,64,0,0),
        eWc, ebc, 64, 1, h, 0, 0, (__hip_bfloat16*)nullptr, ue, h);
  }

  // ---- decoder (batched over 12 steps) ----
  k_gatherE<<<dim3(64,14), 256, 0, stream>>>(embs, h, Eb, Ebt);
  k_mmb <<<dim3(32,7,1), 256, 0, stream>>>(adjb, Ebt, AE1, 896, 4096, 2);
  k_redT<<<dim3(64,14), 256, 0, stream>>>(AE1, (float*)nullptr, (const float*)nullptr, AE1t, 896, 1, 0, 0, 1);
  k_mmb <<<dim3(32,7,1), 256, 0, stream>>>(adjb, AE1t, AE2, 896, 4096, 2);
  k_redT<<<dim3(64,14), 256, 0, stream>>>(AE2, AE2, Eb, (__hip_bfloat16*)nullptr, 896, 1, 1, 1, 0);
  k_ggemm<<<dim3(3072,2), 256, 0, stream>>>(
      S(Eb,896,0,1), S(Eb,896,768,0), S(AE1,896,0,1), S(AE1,896,768,0), S(AE2,896,0,1), S(AE2,896,768,0),
      dWg, dbg, 128, 0, RHb, 768, 1, RHbt, ud, h);
  k_mmb <<<dim3(32,6,1), 256, 0, stream>>>(adjb, RHbt, P1B, 768, 4096, 2);
  k_redT<<<dim3(64,12), 256, 0, stream>>>(P1B, (float*)nullptr, (const float*)nullptr, P1Bt, 768, 1, 0, 0, 1);
  k_mmb <<<dim3(32,6,1), 256, 0, stream>>>(adjb, P1Bt, P2B, 768, 4096, 2);
  k_redT<<<dim3(64,12), 256, 0, stream>>>(P2B, P2B, RHb, (__hip_bfloat16*)nullptr, 768, 1, 1, 1, 0);
  k_ggemm<<<dim3(3072,1), 256, 0, stream>>>(
      S(Eb,896,0,1), S(RHb,768,0,1), S(AE1,896,0,1), S(P1B,768,0,1), S(AE2,896,0,1), S(P2B,768,0,1),
      dWc, dbc, 64, 1, hd, 0, 0, (__hip_bfloat16*)nullptr, ud, h);

  k_pred<<<12288, 256, 0, stream>>>(hd, pw, pb, (float*)d_out);
}

// Round 6
// 6178.563 us; speedup vs baseline: 3.2012x; 1.0046x over previous
//
#include <hip/hip_runtime.h>
#include <hip/hip_bf16.h>
#include <math.h>

// ---------------- problem constants ----------------
#define NN     4096
#define INLEN  564
#define NT     24
#define NC1    32
#define NC2    64
#define KS     10
#define EPS    1e-5f

typedef short s8v __attribute__((ext_vector_type(8)));
typedef short s4v __attribute__((ext_vector_type(4)));
typedef float f4v __attribute__((ext_vector_type(4)));

// ---------------- workspace layout (float offsets) — round-3 layout ----------------
static const long O_COLS   = 0;          // 8960
static const long O_COLSQ  = 8960;       // 8960
static const long O_STATS  = 17920;      // 24*128
static const long O_H      = 20992;      // 4096*64
static const long ZERO_FLOATS = 283136;
static const long O_A1     = 283136;     // 768
static const long O_D1     = 283904;     // 768
static const long O_CB2    = 284672;     // 1536
static const long O_W2B    = 286208;     // bf16 24*10*64*32 -> 122880 float slots
// ---- embedding phase ----
static const long O_G1P    = 532480;     // bf16 4096*280*32 -> 18,350,080 slots
static const long O_Y2     = 18882560;   // bf16 4096*64*68 (PER-T, reused) -> 8,912,896 slots
static const long O_EMBS   = 27795456;   // fp32 24*4096*64 = 6,291,456 -> end 34,086,912
// ---- encoder/decoder overlay (g1p/y2 dead) ----
static const long O_ADJB   = 532480;     // bf16 4096^2 -> 8,388,608 slots
static const long O_PP     = 8921088;    // fp32 4,194,304 (enc partials; decoder hd)
static const long O_X      = 13115392;   // 524288   (decoder: P2B)
static const long O_XT     = 13639680;   // 262144 (bf16 128x4096)
static const long O_T1     = 13901824;   // 524288
static const long O_T1T    = 14426112;   // 262144
static const long O_T2     = 14688256;   // 524288
static const long O_RH     = 15212544;   // 262144
static const long O_RHT    = 15474688;   // 131072 (bf16 64x4096)
static const long O_P1S    = 15605760;   // 262144
static const long O_P1ST   = 15867904;   // 131072
static const long O_P2S    = 15998976;   // 262144
static const long O_UE     = 16261120;   // 131072 (bf16 4096*64)
// ---- decoder ----
static const long O_EB     = 16392192;   // fp32 4096*896 = 3,670,016
static const long O_EBT    = 20062208;   // bf16 896*4096 -> 1,835,008 (reused: RHbt, then P1Bt)
static const long O_AE1    = 21897216;   // 3,670,016
static const long O_AE1T   = 25567232;   // 1,835,008 (reused: ud bf16 49152*64 -> 1,572,864)
static const long O_AE2    = 27795456;   // 3,670,016 (overlays embs, dead by then)
static const long O_RHB    = 31465472;   // 3,145,728
static const long O_P1B    = 34611200;   // 3,145,728 -> peak end 37,756,928 floats = 151.0 MB
static const long O_P2B    = O_X;        // 3,145,728 (enc bufs dead)
static const long O_HD     = O_PP;       // 3,145,728

struct Src { const float* p; int ld; int off; int tmul; };

static __device__ __forceinline__ float cvt_bf(short s) {
  return __uint_as_float(((unsigned)(unsigned short)s) << 16);
}
static __device__ __forceinline__ short bf16bits(float v) {
  __hip_bfloat16_raw r = __hip_bfloat16_raw(__float2bfloat16(v));
  return (short)r.x;
}

// ---------------- conv1: one node per block, input row in LDS (r4 kernel, FIXED) ----
__global__ __launch_bounds__(256) void k_conv1n(const float* __restrict__ inp,
    const float* __restrict__ w1, const float* __restrict__ b1,
    __hip_bfloat16* __restrict__ g1p) {
  __shared__ float xin[INLEN];
  __shared__ float wl[320];
  __shared__ float bl[32];
  int n = blockIdx.x, tid = threadIdx.x;
  for (int i=tid; i<INLEN; i+=256) xin[i] = inp[(long)n*INLEN + i];
  for (int i=tid; i<320; i+=256) wl[i] = w1[i];   // strided: block=256 < 320
  if (tid < 32)  bl[tid] = b1[tid];
  __syncthreads();
  int c = tid & 31, pb = tid >> 5;
  float wreg[KS];
  #pragma unroll
  for (int k=0;k<KS;k++) wreg[k] = wl[c*KS+k];
  float bias = bl[c];
  for (int p = pb; p < 280; p += 8) {
    float acc = 0.f;
    if (p < 278) {
      acc = bias;
      #pragma unroll
      for (int k=0;k<KS;k++) acc = fmaf(wreg[k], xin[2*p+k], acc);
      acc = fmaxf(acc, 0.f);
    }
    g1p[((long)n*280 + p)*32 + c] = __float2bfloat16(acc);
  }
}

// ---------------- BN1 column sums, vectorized (r4 kernel) ----------------
__global__ __launch_bounds__(256) void k_colsum2(const __hip_bfloat16* __restrict__ g1p,
    float* __restrict__ colS, float* __restrict__ colSQ) {
  int gid = blockIdx.x*256 + threadIdx.x;   // 140 blocks: 1120 col-groups x 32 chunks
  int cg = gid % 1120, chunk = gid / 1120;
  int col0 = cg*8;
  float s[8], sq[8];
  #pragma unroll
  for (int j=0;j<8;j++) { s[j]=0.f; sq[j]=0.f; }
  int n0 = chunk*128;
  const short* gp = (const short*)g1p;
  for (int n=n0; n<n0+128; n++) {
    s8v v = *(const s8v*)(gp + (long)n*8960 + col0);
    #pragma unroll
    for (int j=0;j<8;j++) { float f = cvt_bf(v[j]); s[j]+=f; sq[j]+=f*f; }
  }
  #pragma unroll
  for (int j=0;j<8;j++) { atomicAdd(&colS[col0+j], s[j]); atomicAdd(&colSQ[col0+j], sq[j]); }
}

__global__ __launch_bounds__(64) void k_bn1aff(const float* __restrict__ colS,
    const float* __restrict__ colSQ, const float* __restrict__ g, const float* __restrict__ b,
    float* __restrict__ a1, float* __restrict__ d1) {
  int i = blockIdx.x*64 + threadIdx.x;
  if (i >= NT*NC1) return;
  int t = i / NC1, c = i % NC1;
  float s=0.f, sq=0.f;
  for (int p=6*t; p<6*t+140; p++) { s += colS[p*32+c]; sq += colSQ[p*32+c]; }
  float cnt = 4096.f*140.f;
  float m = s/cnt;
  float v = sq/cnt - m*m;
  float a = g[c]*rsqrtf(v+EPS);
  a1[i] = a;
  d1[i] = b[c] - m*a;
}

// ---------------- fold BN1 into conv2 weights: w2b[t][tap][c2][c1] bf16 ----------------
__global__ __launch_bounds__(256) void k_w2b(const float* __restrict__ w2,
    const float* __restrict__ b2, const float* __restrict__ a1, const float* __restrict__ d1,
    __hip_bfloat16* __restrict__ w2b, float* __restrict__ cb2) {
  int i = blockIdx.x*256 + threadIdx.x;   // t*64+c2
  if (i >= NT*NC2) return;
  int t = i>>6, c2 = i&63;
  float cb = b2[c2];
  for (int c1=0;c1<NC1;c1++) {
    float a = a1[t*32+c1], d = d1[t*32+c1];
    float wsum = 0.f;
    for (int k=0;k<KS;k++) {
      float wv = w2[(c2*32+c1)*KS+k];
      wsum += wv;
      w2b[(((long)t*10 + k)*64 + c2)*32 + c1] = __float2bfloat16(wv*a);
    }
    cb += wsum*d;
  }
  cb2[i] = cb;
}

// ---------------- conv2 as 10 accumulated MFMAs (K=c1=32), ONE t per launch ------
__global__ __launch_bounds__(256) void k_conv2m(const __hip_bfloat16* __restrict__ g1p,
    const __hip_bfloat16* __restrict__ w2b, const float* __restrict__ cb2,
    __hip_bfloat16* __restrict__ y2, float* __restrict__ stats, int t) {
  __shared__ __attribute__((aligned(16))) short patch[4*140*40];   // padded rows: 40 shorts = 80B
  __shared__ float sS[64], sQ[64];
  int tid = threadIdx.x, w = tid>>6, lane = tid&63;
  int n0 = blockIdx.x*4;
  if (tid < 64) { sS[tid]=0.f; sQ[tid]=0.f; }
  const short* gp = (const short*)g1p;
  for (int f = tid; f < 2240; f += 256) {          // 4 nodes * 140 rows * 4 chunks
    int nn = f / 560, rr = f % 560;
    int row = rr >> 2, kq = rr & 3;
    s8v v = *(const s8v*)(gp + ((long)(n0+nn)*280 + 6*t + row)*32 + kq*8);
    *(s8v*)&patch[(nn*140 + row)*40 + kq*8] = v;
  }
  __syncthreads();
  int q = lane>>4, m = lane&15;
  f4v acc[5][4];
  #pragma unroll
  for (int a=0;a<5;a++)
    #pragma unroll
    for (int b=0;b<4;b++) acc[a][b] = (f4v){0.f,0.f,0.f,0.f};
  const short* wb = (const short*)w2b + (long)t*10*64*32;
  for (int s=0; s<10; s++) {
    int j = s>>1, r = s&1;
    s8v bfr[4];
    #pragma unroll
    for (int ng=0; ng<4; ng++)
      bfr[ng] = *(const s8v*)(wb + (long)(s*64 + ng*16 + m)*32 + q*8);
    #pragma unroll
    for (int mg=0; mg<5; mg++) {
      int l2 = mg*16 + m;
      int u = l2 + j; u = (u>69)?69:u;
      s8v afr = *(const s8v*)&patch[(w*140 + 2*u + r)*40 + q*8];
      #pragma unroll
      for (int ng=0; ng<4; ng++)
        acc[mg][ng] = __builtin_amdgcn_mfma_f32_16x16x32_bf16(afr, bfr[ng], acc[mg][ng], 0,0,0);
    }
  }
  int node = n0 + w;
  float s1a[4]={0,0,0,0}, s2a[4]={0,0,0,0};
  #pragma unroll
  for (int mg=0; mg<5; mg++) {
    int l2b = mg*16 + q*4;
    #pragma unroll
    for (int ng=0; ng<4; ng++) {
      int c2 = ng*16 + m;
      float cbv = cb2[t*64 + c2];
      float vv[4];
      #pragma unroll
      for (int rr=0; rr<4; rr++) {
        float v = fmaxf(acc[mg][ng][rr] + cbv, 0.f);
        vv[rr] = v;
        if (l2b + rr < 66) { s1a[ng] += v; s2a[ng] += v*v; }
      }
      long base = ((long)node*64 + c2)*68 + l2b;
      if (mg < 4) {
        s4v o;
        #pragma unroll
        for (int rr=0; rr<4; rr++) o[rr] = bf16bits(vv[rr]);
        *(s4v*)((short*)y2 + base) = o;
      } else {
        for (int rr=0; rr<4; rr++) if (l2b+rr < 66) y2[base+rr] = __float2bfloat16(vv[rr]);
      }
    }
  }
  #pragma unroll
  for (int ng=0; ng<4; ng++) {
    atomicAdd(&sS[ng*16+m], s1a[ng]);
    atomicAdd(&sQ[ng*16+m], s2a[ng]);
  }
  __syncthreads();
  if (tid < 64) {
    atomicAdd(&stats[t*128+tid], sS[tid]);
    atomicAdd(&stats[t*128+64+tid], sQ[tid]);
  }
}

// ---------------- BN2 + fcconv + relu + fc, LDS-staged y2 (r4 kernel) ----------------
__global__ __launch_bounds__(256) void k_pass2(const __hip_bfloat16* __restrict__ y2,
    const float* __restrict__ stats, const float* __restrict__ bn2g, const float* __restrict__ bn2b,
    const float* __restrict__ fcvw, const float* __restrict__ fcvb,
    const float* __restrict__ fcW, const float* __restrict__ fcB,
    float* __restrict__ embs, int t) {
  __shared__ __attribute__((aligned(16))) short yb[4*64*68];   // 34816 B
  __shared__ float fw[66*64];
  __shared__ float fwa[64], cfcs[64];
  __shared__ float zbuf[4][68];
  int tid = threadIdx.x;
  int n0 = blockIdx.x*4;
  const short* yg = (const short*)y2;
  for (int f=tid; f<2176; f+=256)
    *(s8v*)&yb[f*8] = *(const s8v*)(yg + (long)n0*64*68 + f*8);
  for (int i=tid; i<66*64; i+=256) fw[i] = fcW[i];
  if (tid < 64) {
    float cnt = 4096.f*66.f;
    float m = stats[t*128+tid]/cnt;
    float v = stats[t*128+64+tid]/cnt - m*m;
    float a = bn2g[tid]*rsqrtf(v+EPS);
    float d = bn2b[tid] - m*a;
    fwa[tid]  = fcvw[tid]*a;
    cfcs[tid] = fcvw[tid]*d;
  }
  __syncthreads();
  float cfc = fcvb[0];
  #pragma unroll 8
  for (int c=0;c<64;c++) cfc += cfcs[c];
  for (int idx=tid; idx<4*66; idx+=256) {
    int nn = idx/66, l = idx%66;
    float z = cfc;
    #pragma unroll 8
    for (int c=0;c<64;c++) z = fmaf(fwa[c], cvt_bf(yb[(nn*64+c)*68 + l]), z);
    zbuf[nn][l] = fmaxf(z, 0.f);
  }
  __syncthreads();
  int nn = tid>>6, e = tid&63;
  float acc = fcB[e];
  for (int l=0;l<66;l++) acc = fmaf(zbuf[nn][l], fw[l*64+e], acc);
  embs[((long)t*NN + n0+nn)*64 + e] = acc;
}

// ---------------- adj fp32 -> bf16 ----------------
__global__ __launch_bounds__(256) void k_cvtadj(const float* __restrict__ adj,
    __hip_bfloat16* __restrict__ adjb) {
  long gid = ((long)blockIdx.x*256 + threadIdx.x)*4;
  float4 v = *(const float4*)(adj + gid);
  adjb[gid+0] = __float2bfloat16(v.x);
  adjb[gid+1] = __float2bfloat16(v.y);
  adjb[gid+2] = __float2bfloat16(v.z);
  adjb[gid+3] = __float2bfloat16(v.w);
}

// ---------------- bf16 MFMA GEMM: P = adjb @ Bt^T (round-3 kernel, verbatim) ----------
__global__ __launch_bounds__(256) void k_mmb(const __hip_bfloat16* __restrict__ A,
    const __hip_bfloat16* __restrict__ Bt, float* __restrict__ P,
    int N, int kchunk, int nwn) {
  __shared__ __attribute__((aligned(16))) short As[4*256*8];
  __shared__ __attribute__((aligned(16))) short Bs[4*128*8];
  int tid = threadIdx.x;
  int w = tid >> 6, lane = tid & 63;
  int bmsh = (nwn==2) ? 7 : 8;
  int BM = 1 << bmsh;
  int BN = nwn << 6;
  int wm = (nwn==2) ? (w>>1) : w;
  int wn = (nwn==2) ? (w&1) : 0;
  long Mb = (long)blockIdx.x << bmsh;
  int Nb = blockIdx.y * BN;
  int k0 = blockIdx.z * kchunk;
  const short* Ag = (const short*)A;
  const short* Bg = (const short*)Bt;
  f4v acc[4][4];
  #pragma unroll
  for (int i=0;i<4;i++)
    #pragma unroll
    for (int j=0;j<4;j++) acc[i][j] = (f4v){0.f,0.f,0.f,0.f};
  int q = lane >> 4, m = lane & 15;
  for (int kc=k0; kc<k0+kchunk; kc+=32) {
    __syncthreads();
    for (int f = tid; f < (BM<<2); f += 256) {
      int row = f >> 2, qq = f & 3;
      s8v v = *(const s8v*)(Ag + (Mb + row)*4096 + kc + qq*8);
      *(s8v*)&As[((qq<<bmsh) + row)*8] = v;
    }
    for (int f = tid; f < (BN<<2); f += 256) {
      int col = f >> 2, qq = f & 3;
      s8v v = *(const s8v*)(Bg + (long)(Nb + col)*4096 + kc + qq*8);
      *(s8v*)&Bs[(qq*BN + col)*8] = v;
    }
    __syncthreads();
    s8v af[4], bf[4];
    #pragma unroll
    for (int i=0;i<4;i++) af[i] = *(const s8v*)&As[((q<<bmsh) + wm*64 + i*16 + m)*8];
    #pragma unroll
    for (int j=0;j<4;j++) bf[j] = *(const s8v*)&Bs[(q*BN + wn*64 + j*16 + m)*8];
    #pragma unroll
    for (int i=0;i<4;i++)
      #pragma unroll
      for (int j=0;j<4;j++)
        acc[i][j] = __builtin_amdgcn_mfma_f32_16x16x32_bf16(af[i], bf[j], acc[i][j], 0, 0, 0);
  }
  float* pp = P + (long)blockIdx.z * 4096L * N;
  #pragma unroll
  for (int i=0;i<4;i++) {
    long row0 = Mb + wm*64 + i*16 + q*4;
    #pragma unroll
    for (int j=0;j<4;j++) {
      int col = Nb + wn*64 + j*16 + m;
      #pragma unroll
      for (int r=0;r<4;r++)
        pp[(row0 + r)*N + col] = acc[i][j][r];
    }
  }
}

// ---------------- split-K reduce + optional (2x-ref) + optional bf16T (round-3) -------
__global__ __launch_bounds__(256) void k_redT(const float* __restrict__ P,
    float* __restrict__ dst, const float* __restrict__ ref,
    __hip_bfloat16* __restrict__ dstT, int ldc, int ksplit, int mode,
    int writeF, int writeT) {
  __shared__ float tile[64][65];
  int tid = threadIdx.x;
  int n0 = blockIdx.x*64, c0 = blockIdx.y*64;
  long total = 4096L*ldc;
  for (int i=0; i<16; i++) {
    int flat = i*256 + tid;
    int cc = flat & 63, nn = flat >> 6;
    long idx = (long)(n0+nn)*ldc + c0+cc;
    float v = P[idx];
    for (int s=1; s<ksplit; s++) v += P[(long)s*total + idx];
    if (mode) v = 2.f*v - ref[idx];
    if (writeF) dst[idx] = v;
    tile[nn][cc] = v;
  }
  __syncthreads();
  if (writeT) {
    for (int i=0; i<16; i++) {
      int flat = i*256 + tid;
      int nn = flat & 63, cc = flat >> 6;
      dstT[(long)(c0+cc)*4096 + n0+nn] = __float2bfloat16(tile[nn][cc]);
    }
  }
}

// ---------------- X = [et|h] fp32 + Xt bf16 transposed (round-3) ----------------
__global__ __launch_bounds__(256) void k_buildXT(const float* __restrict__ et,
    const float* __restrict__ h, float* __restrict__ X, __hip_bfloat16* __restrict__ Xt) {
  __shared__ float tile[64][65];
  int tid = threadIdx.x;
  int n0 = blockIdx.x*64, c0 = blockIdx.y*64;
  for (int i=0; i<16; i++) {
    int flat = i*256 + tid;
    int cc = flat & 63, nn = flat >> 6;
    int col = c0 + cc, n = n0 + nn;
    float v = (col < 64) ? et[(long)n*64 + col] : h[(long)n*64 + (col-64)];
    X[(long)n*128 + col] = v;
    tile[nn][cc] = v;
  }
  __syncthreads();
  for (int i=0; i<16; i++) {
    int flat = i*256 + tid;
    int nn = flat & 63, cc = flat >> 6;
    Xt[(long)(c0+cc)*4096 + n0+nn] = __float2bfloat16(tile[nn][cc]);
  }
}

// ---------------- Eb = [emb12..23 | h | 0pad] fp32 ld896 + Ebt bf16 (round-3) ---------
__global__ __launch_bounds__(256) void k_gatherE(const float* __restrict__ embs,
    const float* __restrict__ h, float* __restrict__ Eb, __hip_bfloat16* __restrict__ Ebt) {
  __shared__ float tile[64][65];
  int tid = threadIdx.x;
  int n0 = blockIdx.x*64, c0 = blockIdx.y*64;
  for (int i=0; i<16; i++) {
    int flat = i*256 + tid;
    int cc = flat & 63, nn = flat >> 6;
    int col = c0 + cc, n = n0 + nn;
    float v;
    if (col < 768)      v = embs[((long)(12 + (col>>6))*NN + n)*64 + (col & 63)];
    else if (col < 832) v = h[(long)n*64 + (col - 768)];
    else                v = 0.f;
    Eb[(long)n*896 + col] = v;
    tile[nn][cc] = v;
  }
  __syncthreads();
  for (int i=0; i<16; i++) {
    int flat = i*256 + tid;
    int nn = flat & 63, cc = flat >> 6;
    Ebt[(long)(c0+cc)*4096 + n0+nn] = __float2bfloat16(tile[nn][cc]);
  }
}

// ---------------- gather-GEMM + fused DCGRU epilogue (round-3) ----------------
__global__ __launch_bounds__(256) void k_ggemm(
    Src s0, Src s1, Src s2, Src s3, Src s4, Src s5,
    const float* __restrict__ W, const float* __restrict__ bias, int N, int mode,
    float* __restrict__ o1, int ld1, int t1, __hip_bfloat16* __restrict__ o1t,
    __hip_bfloat16* __restrict__ o2, const float* __restrict__ h) {
  __shared__ float Ags[32][17];
  __shared__ float Bgs[32][64];
  int tid = threadIdx.x;
  int Mb = blockIdx.x*16, Nb = blockIdx.y*64;
  float acc[4] = {0.f,0.f,0.f,0.f};
  for (int c0=0; c0<384; c0+=32) {
    Src S;
    switch (c0 >> 6) {
      case 0: S = s0; break; case 1: S = s1; break; case 2: S = s2; break;
      case 3: S = s3; break; case 4: S = s4; break; default: S = s5; break;
    }
    int cc0 = c0 & 63;
    __syncthreads();
    #pragma unroll
    for (int h0=0; h0<2; h0++) {
      int idx = tid + h0*256;
      int mm_ = idx >> 5, kk = idx & 31;
      int row = Mb + mm_, tt = row >> 12, n = row & 4095;
      Ags[kk][mm_] = S.p[(long)n*S.ld + S.off + S.tmul*(tt*64) + cc0 + kk];
    }
    #pragma unroll
    for (int j=0;j<8;j++) {
      int kk = (tid >> 6) + j*4;
      Bgs[kk][tid & 63] = W[(long)(c0+kk)*N + Nb + (tid & 63)];
    }
    __syncthreads();
    #pragma unroll
    for (int kk=0;kk<32;kk++) {
      float a = Ags[kk][tid >> 4];
      const float4 b4 = *(const float4*)&Bgs[kk][(tid & 15)*4];
      acc[0] = fmaf(a, b4.x, acc[0]);
      acc[1] = fmaf(a, b4.y, acc[1]);
      acc[2] = fmaf(a, b4.z, acc[2]);
      acc[3] = fmaf(a, b4.w, acc[3]);
    }
  }
  int row = Mb + (tid >> 4), tt = row >> 12, n = row & 4095;
  #pragma unroll
  for (int j=0;j<4;j++) {
    int col = Nb + (tid & 15)*4 + j;
    float g = acc[j] + bias[col];
    if (mode == 0) {
      float sg = 1.f/(1.f + expf(-g));
      if (col < 64) {
        float v = sg * h[(long)n*64 + col];
        o1[(long)n*ld1 + (long)t1*tt*64 + col] = v;
        o1t[((long)t1*tt*64 + col)*4096 + n] = __float2bfloat16(v);
      } else {
        o2[(long)row*64 + (col - 64)] = __float2bfloat16(sg);
      }
    } else {
      float uu = __bfloat162float(o2[(long)row*64 + col]);
      o1[(long)row*64 + col] = uu*h[(long)n*64 + col] + (1.f - uu)*tanhf(g);
    }
  }
}

// ---------------- preds ----------------
__global__ __launch_bounds__(256) void k_pred(const float* __restrict__ hd,
    const float* __restrict__ pw, const float* __restrict__ pb, float* __restrict__ out) {
  int gid = blockIdx.x*256 + threadIdx.x;
  int wid = gid >> 6;
  int lane = threadIdx.x & 63;
  if (wid >= 12*NN) return;
  int t = wid >> 12, n = wid & 4095;
  float hv = hd[(long)wid*64 + lane];
  float res = 0.f;
  #pragma unroll
  for (int p=0;p<12;p++) {
    float v = hv * pw[lane*12 + p];
    #pragma unroll
    for (int off=32; off>0; off>>=1) v += __shfl_xor(v, off, 64);
    if (lane == p) res = v + pb[p];
  }
  if (lane < 12) out[(long)n*144 + t*12 + lane] = res;
}

// ============================================================================
extern "C" void kernel_launch(void* const* d_in, const int* in_sizes, int n_in,
                              void* d_out, int out_size, void* d_ws, size_t ws_size,
                              hipStream_t stream) {
  const float* inp  = (const float*)d_in[0];
  const float* c1w  = (const float*)d_in[2];
  const float* c1b  = (const float*)d_in[3];
  const float* c2w  = (const float*)d_in[4];
  const float* c2b  = (const float*)d_in[5];
  const float* bn1g = (const float*)d_in[6];
  const float* bn1b = (const float*)d_in[7];
  const float* bn2g = (const float*)d_in[8];
  const float* bn2b = (const float*)d_in[9];
  const float* fcvw = (const float*)d_in[10];
  const float* fcvb = (const float*)d_in[11];
  const float* fcW  = (const float*)d_in[12];
  const float* fcB  = (const float*)d_in[13];
  const float* eWg  = (const float*)d_in[14];
  const float* ebg  = (const float*)d_in[15];
  const float* eWc  = (const float*)d_in[16];
  const float* ebc  = (const float*)d_in[17];
  const float* dWg  = (const float*)d_in[18];
  const float* dbg  = (const float*)d_in[19];
  const float* dWc  = (const float*)d_in[20];
  const float* dbc  = (const float*)d_in[21];
  const float* pw   = (const float*)d_in[22];
  const float* pb   = (const float*)d_in[23];
  const float* adj  = (const float*)d_in[n_in-1];
  for (int i=0;i<n_in;i++) if (in_sizes[i] == NN*NN) adj = (const float*)d_in[i];

  float* ws = (float*)d_ws;
  float* colS  = ws + O_COLS;
  float* colSQ = ws + O_COLSQ;
  float* stats = ws + O_STATS;
  float* h     = ws + O_H;
  float* a1    = ws + O_A1;
  float* d1    = ws + O_D1;
  float* cb2   = ws + O_CB2;
  __hip_bfloat16* w2b = (__hip_bfloat16*)(ws + O_W2B);
  __hip_bfloat16* g1p = (__hip_bfloat16*)(ws + O_G1P);
  __hip_bfloat16* y2  = (__hip_bfloat16*)(ws + O_Y2);
  float* embs  = ws + O_EMBS;
  __hip_bfloat16* adjb = (__hip_bfloat16*)(ws + O_ADJB);
  float* Pp    = ws + O_PP;
  float* X     = ws + O_X;
  __hip_bfloat16* Xt  = (__hip_bfloat16*)(ws + O_XT);
  float* T1    = ws + O_T1;
  __hip_bfloat16* T1t = (__hip_bfloat16*)(ws + O_T1T);
  float* T2    = ws + O_T2;
  float* rh    = ws + O_RH;
  __hip_bfloat16* rht = (__hip_bfloat16*)(ws + O_RHT);
  float* P1s   = ws + O_P1S;
  __hip_bfloat16* P1st = (__hip_bfloat16*)(ws + O_P1ST);
  float* P2s   = ws + O_P2S;
  __hip_bfloat16* ue  = (__hip_bfloat16*)(ws + O_UE);
  float* Eb    = ws + O_EB;
  __hip_bfloat16* Ebt = (__hip_bfloat16*)(ws + O_EBT);   // later RHbt, then P1Bt
  float* AE1   = ws + O_AE1;
  __hip_bfloat16* AE1t = (__hip_bfloat16*)(ws + O_AE1T); // later ud
  float* AE2   = ws + O_AE2;
  float* RHb   = ws + O_RHB;
  float* P1B   = ws + O_P1B;
  float* P2B   = ws + O_P2B;
  float* hd    = ws + O_HD;
  __hip_bfloat16* RHbt = Ebt;
  __hip_bfloat16* P1Bt = Ebt;
  __hip_bfloat16* ud   = AE1t;

  auto S = [](const float* p, int ld, int off, int tmul){ Src s; s.p=p; s.ld=ld; s.off=off; s.tmul=tmul; return s; };

  hipMemsetAsync(ws, 0, ZERO_FLOATS*sizeof(float), stream);

  // ---- embedding ----
  k_conv1n<<<4096, 256, 0, stream>>>(inp, c1w, c1b, g1p);
  k_colsum2<<<140, 256, 0, stream>>>(g1p, colS, colSQ);
  k_bn1aff<<<12, 64, 0, stream>>>(colS, colSQ, bn1g, bn1b, a1, d1);
  k_w2b   <<<6, 256, 0, stream>>>(c2w, c2b, a1, d1, w2b, cb2);
  for (int t=0; t<NT; t++) {
    k_conv2m<<<1024, 256, 0, stream>>>(g1p, w2b, cb2, y2, stats, t);
    k_pass2 <<<1024, 256, 0, stream>>>(y2, stats, bn2g, bn2b, fcvw, fcvb, fcW, fcB, embs, t);
  }

  // ---- adj -> bf16 (g1p dead now) ----
  k_cvtadj<<<16384, 256, 0, stream>>>(adj, adjb);

  // ---- encoder (round-3 path, verbatim) ----
  for (int t=0; t<12; t++) {
    const float* et = embs + (long)t*NN*64;
    k_buildXT<<<dim3(64,2), 256, 0, stream>>>(et, h, X, Xt);
    k_mmb <<<dim3(32,1,8), 256, 0, stream>>>(adjb, Xt, Pp, 128, 512, 2);
    k_redT<<<dim3(64,2), 256, 0, stream>>>(Pp, T1, (const float*)nullptr, T1t, 128, 8, 0, 1, 1);
    k_mmb <<<dim3(32,1,8), 256, 0, stream>>>(adjb, T1t, Pp, 128, 512, 2);
    k_redT<<<dim3(64,2), 256, 0, stream>>>(Pp, T2, X, (__hip_bfloat16*)nullptr, 128, 8, 1, 1, 0);
    k_ggemm<<<dim3(256,2), 256, 0, stream>>>(
        S(X,128,0,0), S(X,128,64,0), S(T1,128,0,0), S(T1,128,64,0), S(T2,128,0,0), S(T2,128,64,0),
        eWg, ebg, 128, 0, rh, 64, 0, rht, ue, h);
    k_mmb <<<dim3(16,1,8), 256, 0, stream>>>(adjb, rht, Pp, 64, 512, 1);
    k_redT<<<dim3(64,1), 256, 0, stream>>>(Pp, P1s, (const float*)nullptr, P1st, 64, 8, 0, 1, 1);
    k_mmb <<<dim3(16,1,8), 256, 0, stream>>>(adjb, P1st, Pp, 64, 512, 1);
    k_redT<<<dim3(64,1), 256, 0, stream>>>(Pp, P2s, rh, (__hip_bfloat16*)nullptr, 64, 8, 1, 1, 0);
    k_ggemm<<<dim3(256,1), 256, 0, stream>>>(
        S(et,64,0,0), S(rh,64,0,0), S(T1,128,0,0), S(P1s,64,0,0), S(T2,128,0,0), S(P2s,64,0,0),
        eWc, ebc, 64, 1, h, 0, 0, (__hip_bfloat16*)nullptr, ue, h);
  }

  // ---- decoder (round-3 path, verbatim) ----
  k_gatherE<<<dim3(64,14), 256, 0, stream>>>(embs, h, Eb, Ebt);
  k_mmb <<<dim3(32,7,1), 256, 0, stream>>>(adjb, Ebt, AE1, 896, 4096, 2);
  k_redT<<<dim3(64,14), 256, 0, stream>>>(AE1, (float*)nullptr, (const float*)nullptr, AE1t, 896, 1, 0, 0, 1);
  k_mmb <<<dim3(32,7,1), 256, 0, stream>>>(adjb, AE1t, AE2, 896, 4096, 2);
  k_redT<<<dim3(64,14), 256, 0, stream>>>(AE2, AE2, Eb, (__hip_bfloat16*)nullptr, 896, 1, 1, 1, 0);
  k_ggemm<<<dim3(3072,2), 256, 0, stream>>>(
      S(Eb,896,0,1), S(Eb,896,768,0), S(AE1,896,0,1), S(AE1,896,768,0), S(AE2,896,0,1), S(AE2,896,768,0),
      dWg, dbg, 128, 0, RHb, 768, 1, RHbt, ud, h);
  k_mmb <<<dim3(32,6,1), 256, 0, stream>>>(adjb, RHbt, P1B, 768, 4096, 2);
  k_redT<<<dim3(64,12), 256, 0, stream>>>(P1B, (float*)nullptr, (const float*)nullptr, P1Bt, 768, 1, 0, 0, 1);
  k_mmb <<<dim3(32,6,1), 256, 0, stream>>>(adjb, P1Bt, P2B, 768, 4096, 2);
  k_redT<<<dim3(64,12), 256, 0, stream>>>(P2B, P2B, RHb, (__hip_bfloat16*)nullptr, 768, 1, 1, 1, 0);
  k_ggemm<<<dim3(3072,1), 256, 0, stream>>>(
      S(Eb,896,0,1), S(RHb,768,0,1), S(AE1,896,0,1), S(P1B,768,0,1), S(AE2,896,0,1), S(P2B,768,0,1),
      dWc, dbc, 64, 1, hd, 0, 0, (__hip_bfloat16*)nullptr, ud, h);

  k_pred<<<12288, 256, 0, stream>>>(hd, pw, pb, (float*)d_out);
}